// Round 3
// baseline (788.732 us; speedup 1.0000x reference)
//
#include <hip/hip_runtime.h>

typedef short bf16x8 __attribute__((ext_vector_type(8)));
typedef float f32x4  __attribute__((ext_vector_type(4)));
typedef unsigned short u16;

#define NB    32
#define NH    128
#define DV    512
#define DQK   576
#define NKV   8192
#define NTOP  2048
#define SCALE 0.041666666666666664f   // 1/sqrt(576) = 1/24

// workspace element offsets (bytes)
#define OFF_S   0u                    // fp32 [32][128][2048]   33554432 B
#define OFF_P   33554432u             // bf16 [32][128][2048]   16777216 B
#define OFF_QB  50331648u             // bf16 [32][128][576]     4718592 B
#define OFF_KB  55050240u             // bf16 [32][2048][576]   75497472 B
#define OFF_VT  130547712u            // bf16 [32][512][2048]   67108864 B
#define OFF_OP  197656576u            // fp32 [4][32][128][512] 33554432 B

__device__ __forceinline__ unsigned bfbits(float x) {
  union { float f; unsigned u; } c; c.f = x;
  return (c.u + 0x7FFFu + ((c.u >> 16) & 1u)) >> 16;   // RNE; inputs never NaN
}
__device__ __forceinline__ unsigned pk2(float x, float y) {
  return bfbits(x) | (bfbits(y) << 16);
}

// ---------------- cvt_q: Q fp32 -> bf16, 2359296 elems ----------------
__global__ __launch_bounds__(256) void cvt_q(const float* __restrict__ Q, u16* __restrict__ Qb) {
  int i = (blockIdx.x * 256 + threadIdx.x) * 8;
  float4 a = *(const float4*)(Q + i), b = *(const float4*)(Q + i + 4);
  uint4 o = { pk2(a.x, a.y), pk2(a.z, a.w), pk2(b.x, b.y), pk2(b.z, b.w) };
  *(uint4*)(Qb + i) = o;
}

// ---------------- gather_cvt: Kb[b][j][576] bf16 and Vt[b][d][2048] bf16 ----------------
__global__ __launch_bounds__(256) void gather_cvt(const float* __restrict__ KV, const int* __restrict__ Idx,
                                                  u16* __restrict__ Kb, u16* __restrict__ Vt) {
  __shared__ u16 T[128 * 136];        // [128 d][128 k + pad], rows 16B-aligned
  int nt = blockIdx.x, b = blockIdx.y;
  int j0 = nt * 128;
  int t = threadIdx.x;
  const int* idxp = Idx + b * NTOP + j0;
  const float* KVb = KV + (size_t)b * NKV * DQK;
  u16* Kbb = Kb + ((size_t)b * NTOP + j0) * DQK;

  int kq = (t & 31) * 4, dq = (t >> 5) * 16;
  int4 id4 = *(const int4*)&idxp[kq];
  const float* r0 = KVb + (size_t)id4.x * DQK + dq;
  const float* r1 = KVb + (size_t)id4.y * DQK + dq;
  const float* r2 = KVb + (size_t)id4.z * DQK + dq;
  const float* r3 = KVb + (size_t)id4.w * DQK + dq;

  int sd = t >> 1, skh = (t & 1) * 64;      // store-phase mapping

  for (int c = 0; c < 4; ++c) {             // 4 d-chunks of 128
    int co = c * 128;
    unsigned rr[4][16];
#pragma unroll
    for (int i = 0; i < 4; ++i) {
      const float* rp = (i == 0) ? r0 : (i == 1) ? r1 : (i == 2) ? r2 : r3;
      float4 x0 = *(const float4*)(rp + co + 0);
      float4 x1 = *(const float4*)(rp + co + 4);
      float4 x2 = *(const float4*)(rp + co + 8);
      float4 x3 = *(const float4*)(rp + co + 12);
      rr[i][0] = bfbits(x0.x); rr[i][1] = bfbits(x0.y); rr[i][2]  = bfbits(x0.z); rr[i][3]  = bfbits(x0.w);
      rr[i][4] = bfbits(x1.x); rr[i][5] = bfbits(x1.y); rr[i][6]  = bfbits(x1.z); rr[i][7]  = bfbits(x1.w);
      rr[i][8] = bfbits(x2.x); rr[i][9] = bfbits(x2.y); rr[i][10] = bfbits(x2.z); rr[i][11] = bfbits(x2.w);
      rr[i][12] = bfbits(x3.x); rr[i][13] = bfbits(x3.y); rr[i][14] = bfbits(x3.z); rr[i][15] = bfbits(x3.w);
    }
    // Kb writes: row-major, 16 bf16 per row at col co+dq
#pragma unroll
    for (int i = 0; i < 4; ++i) {
      uint4 w0 = { rr[i][0] | (rr[i][1] << 16), rr[i][2] | (rr[i][3] << 16),
                   rr[i][4] | (rr[i][5] << 16), rr[i][6] | (rr[i][7] << 16) };
      uint4 w1 = { rr[i][8] | (rr[i][9] << 16), rr[i][10] | (rr[i][11] << 16),
                   rr[i][12] | (rr[i][13] << 16), rr[i][14] | (rr[i][15] << 16) };
      u16* kp = Kbb + (size_t)(kq + i) * DQK + co + dq;
      *(uint4*)kp = w0; *(uint4*)(kp + 8) = w1;
    }
    // LDS transpose: T[d][k], 4 keys packed per b64 write (conflict-free)
#pragma unroll
    for (int i2 = 0; i2 < 16; ++i2) {
      uint2 w = { rr[0][i2] | (rr[1][i2] << 16), rr[2][i2] | (rr[3][i2] << 16) };
      *(uint2*)&T[(dq + i2) * 136 + kq] = w;
    }
    __syncthreads();
    // store: Vt[b][co+d][j0 + k] coalesced-ish rows
    u16* vp = Vt + ((size_t)b * DV + co + sd) * NTOP + j0 + skh;
    const u16* tp = &T[sd * 136 + skh];
#pragma unroll
    for (int c2 = 0; c2 < 8; ++c2)
      *(uint4*)(vp + c2 * 8) = *(const uint4*)(tp + c2 * 8);
    __syncthreads();
  }

  // tail: cols 512..576 -> Kb only
  int row = t >> 1, half = t & 1;
  int idx = idxp[row];
  const float* src = KVb + (size_t)idx * DQK + 512 + half * 32;
  u16* dst = Kbb + (size_t)row * DQK + 512 + half * 32;
  unsigned u[16];
#pragma unroll
  for (int q = 0; q < 8; ++q) {
    float4 x = *(const float4*)(src + q * 4);
    u[q * 2] = pk2(x.x, x.y); u[q * 2 + 1] = pk2(x.z, x.w);
  }
#pragma unroll
  for (int q = 0; q < 4; ++q) {
    uint4 w = { u[q * 4], u[q * 4 + 1], u[q * 4 + 2], u[q * 4 + 3] };
    *(uint4*)(dst + q * 8) = w;
  }
}

// ---------------- shared NT-GEMM: C[128 x 128] = A[128 x K] . B[128 x K]^T, bf16 in, fp32 out ----------------
template <int NKI, int LD>
__global__ __launch_bounds__(256) void gemm_nt(const u16* __restrict__ A, const u16* __restrict__ B,
                                               float* __restrict__ C, int ldc,
                                               int aB, int bB, int bT, int cB, int cT, int cK, int KS,
                                               float scale) {
  __shared__ u16 As[128 * 32];
  __shared__ u16 Bs[128 * 32];
  int nt = blockIdx.x, b = blockIdx.y, ks = blockIdx.z;
  const u16* Ab = A + (size_t)b * aB + (size_t)ks * KS;
  const u16* Bb = B + (size_t)b * bB + (size_t)nt * bT + (size_t)ks * KS;
  float* Cb = C + (size_t)b * cB + (size_t)nt * cT + (size_t)ks * cK;

  int t = threadIdx.x;
  int r0 = t >> 2, kq = (t & 3) * 8;
  const u16* ag = Ab + (size_t)r0 * LD + kq;
  const u16* bg = Bb + (size_t)r0 * LD + kq;
  u16* aw = &As[r0 * 32 + kq];
  u16* bw = &Bs[r0 * 32 + kq];

  int lane = t & 63, wv = t >> 6;
  int wm = wv & 1, wn = wv >> 1;
  int m16 = lane & 15, quad = lane >> 4;

  uint4 ra0 = *(const uint4*)(ag);
  uint4 ra1 = *(const uint4*)(ag + (size_t)64 * LD);
  uint4 rb0 = *(const uint4*)(bg);
  uint4 rb1 = *(const uint4*)(bg + (size_t)64 * LD);

  f32x4 acc[4][4] = {};

  for (int kk = 0; kk < NKI; ++kk) {
    __syncthreads();
    *(uint4*)aw = ra0; *(uint4*)(aw + 64 * 32) = ra1;
    *(uint4*)bw = rb0; *(uint4*)(bw + 64 * 32) = rb1;
    __syncthreads();
    if (kk + 1 < NKI) {
      const u16* an = ag + (kk + 1) * 32;
      const u16* bn = bg + (kk + 1) * 32;
      ra0 = *(const uint4*)(an);
      ra1 = *(const uint4*)(an + (size_t)64 * LD);
      rb0 = *(const uint4*)(bn);
      rb1 = *(const uint4*)(bn + (size_t)64 * LD);
    }
    bf16x8 af[4], bfr[4];
#pragma unroll
    for (int i = 0; i < 4; ++i) af[i]  = *(const bf16x8*)&As[(wm * 64 + i * 16 + m16) * 32 + quad * 8];
#pragma unroll
    for (int j = 0; j < 4; ++j) bfr[j] = *(const bf16x8*)&Bs[(wn * 64 + j * 16 + m16) * 32 + quad * 8];
#pragma unroll
    for (int i = 0; i < 4; ++i)
#pragma unroll
      for (int j = 0; j < 4; ++j)
        acc[i][j] = __builtin_amdgcn_mfma_f32_16x16x32_bf16(af[i], bfr[j], acc[i][j], 0, 0, 0);
  }

#pragma unroll
  for (int i = 0; i < 4; ++i)
#pragma unroll
    for (int j = 0; j < 4; ++j)
#pragma unroll
      for (int r = 0; r < 4; ++r) {
        int m = wm * 64 + i * 16 + quad * 4 + r;
        int n = wn * 64 + j * 16 + m16;
        Cb[(size_t)m * ldc + n] = acc[i][j][r] * scale;
      }
}

// ---------------- softmax over 2048, write normalized bf16 P ----------------
__global__ __launch_bounds__(256) void softmax_k(const float* __restrict__ S, u16* __restrict__ P) {
  int row = blockIdx.x;                    // b*128 + h
  const float* s = S + (size_t)row * NTOP;
  u16* p = P + (size_t)row * NTOP;
  int t = threadIdx.x;
  int lane = t & 63, wv = t >> 6;
  __shared__ float red[4];

  float4 v0 = *(const float4*)(s + t * 4);
  float4 v1 = *(const float4*)(s + 1024 + t * 4);

  float lm = fmaxf(fmaxf(fmaxf(v0.x, v0.y), fmaxf(v0.z, v0.w)),
                   fmaxf(fmaxf(v1.x, v1.y), fmaxf(v1.z, v1.w)));
  for (int off = 32; off > 0; off >>= 1) lm = fmaxf(lm, __shfl_down(lm, off));
  if (lane == 0) red[wv] = lm;
  __syncthreads();
  float m = fmaxf(fmaxf(red[0], red[1]), fmaxf(red[2], red[3]));

  float e0 = expf(v0.x - m), e1 = expf(v0.y - m), e2 = expf(v0.z - m), e3 = expf(v0.w - m);
  float e4 = expf(v1.x - m), e5 = expf(v1.y - m), e6 = expf(v1.z - m), e7 = expf(v1.w - m);
  float ls = ((e0 + e1) + (e2 + e3)) + ((e4 + e5) + (e6 + e7));
  for (int off = 32; off > 0; off >>= 1) ls += __shfl_down(ls, off);
  __syncthreads();
  if (lane == 0) red[wv] = ls;
  __syncthreads();
  float inv = 1.0f / (((red[0] + red[1]) + (red[2] + red[3])));

  uint2 o0 = { pk2(e0 * inv, e1 * inv), pk2(e2 * inv, e3 * inv) };
  uint2 o1 = { pk2(e4 * inv, e5 * inv), pk2(e6 * inv, e7 * inv) };
  *(uint2*)(p + t * 4) = o0;
  *(uint2*)(p + 1024 + t * 4) = o1;
}

// ---------------- reduce K-split partials -> Out ----------------
__global__ __launch_bounds__(256) void reduce4(const float* __restrict__ Op, float* __restrict__ Out) {
  size_t i = ((size_t)blockIdx.x * 256 + threadIdx.x) * 4;
  const size_t STRIDE = (size_t)NB * NH * DV;   // 2097152
  float4 s0 = *(const float4*)(Op + i);
  float4 s1 = *(const float4*)(Op + STRIDE + i);
  float4 s2 = *(const float4*)(Op + 2 * STRIDE + i);
  float4 s3 = *(const float4*)(Op + 3 * STRIDE + i);
  float4 o = { (s0.x + s1.x) + (s2.x + s3.x), (s0.y + s1.y) + (s2.y + s3.y),
               (s0.z + s1.z) + (s2.z + s3.z), (s0.w + s1.w) + (s2.w + s3.w) };
  *(float4*)(Out + i) = o;
}

extern "C" void kernel_launch(void* const* d_in, const int* in_sizes, int n_in,
                              void* d_out, int out_size, void* d_ws, size_t ws_size,
                              hipStream_t stream) {
  const float* Q  = (const float*)d_in[0];
  const float* KV = (const float*)d_in[1];
  const int*  Idx = (const int*)d_in[2];

  char* ws = (char*)d_ws;
  float* S   = (float*)(ws + OFF_S);
  u16*   P   = (u16*)(ws + OFF_P);
  u16*   Qb  = (u16*)(ws + OFF_QB);
  u16*   Kb  = (u16*)(ws + OFF_KB);
  u16*   Vt  = (u16*)(ws + OFF_VT);
  float* Op  = (float*)(ws + OFF_OP);
  float* Out = (float*)d_out;

  cvt_q<<<dim3(1152), dim3(256), 0, stream>>>(Q, Qb);
  gather_cvt<<<dim3(16, 32), dim3(256), 0, stream>>>(KV, Idx, Kb, Vt);
  // QK^T: per b: M=128 h, N=2048 keys (16 tiles), K=576
  gemm_nt<18, 576><<<dim3(16, 32, 1), dim3(256), 0, stream>>>(
      Qb, Kb, S, NTOP,
      /*aB*/ NH * DQK, /*bB*/ NTOP * DQK, /*bT*/ 128 * DQK,
      /*cB*/ NH * NTOP, /*cT*/ 128, /*cK*/ 0, /*KS*/ 0, SCALE);
  softmax_k<<<dim3(NB * NH), dim3(256), 0, stream>>>(S, P);
  // PV: per b: M=128 h, N=512 d (4 tiles), K=2048 split 4x512
  gemm_nt<16, 2048><<<dim3(4, 32, 4), dim3(256), 0, stream>>>(
      P, Vt, Op, DV,
      /*aB*/ NH * NTOP, /*bB*/ DV * NTOP, /*bT*/ 128 * NTOP,
      /*cB*/ NH * DV, /*cT*/ 128, /*cK*/ NB * NH * DV, /*KS*/ 512, 1.0f);
  reduce4<<<dim3(2048), dim3(256), 0, stream>>>(Op, Out);
}

// Round 4
// 757.237 us; speedup vs baseline: 1.0416x; 1.0416x over previous
//
#include <hip/hip_runtime.h>

typedef short bf16x8 __attribute__((ext_vector_type(8)));
typedef float f32x4  __attribute__((ext_vector_type(4)));
typedef unsigned short u16;

#define NB    32
#define NH    128
#define DV    512
#define DQK   576
#define NKV   8192
#define NTOP  2048
#define NCH   16          // key chunks
#define KC    128         // keys per chunk
#define PSTR  136         // Psh row stride (bf16 elems)
#define SCALE 0.041666666666666664f   // 1/sqrt(576) = 1/24

// workspace byte offsets
#define OFF_OP 0u           // fp32 [16][32][128][512] = 134217728 B
#define OFF_M  134217728u   // fp32 [32][16][128]      = 262144 B
#define OFF_L  134479872u   // fp32 [32][16][128]      = 262144 B

__device__ __forceinline__ unsigned bfbits(float x) {
  union { float f; unsigned u; } c; c.f = x;
  return (c.u + 0x7FFFu + ((c.u >> 16) & 1u)) >> 16;   // RNE; inputs never NaN
}
__device__ __forceinline__ unsigned pk2(float x, float y) {
  return bfbits(x) | (bfbits(y) << 16);
}

// ---------------- fused flash chunk: per (b, ks): S=QK^T -> chunk softmax -> O_p = P V ----------------
__global__ __launch_bounds__(256) void flash_chunk(const float* __restrict__ Q, const float* __restrict__ KV,
                                                   const int* __restrict__ Idx,
                                                   float* __restrict__ Op, float* __restrict__ Mg,
                                                   float* __restrict__ Lg) {
  __shared__ u16 Psh[128 * PSTR];   // P tile [128h][128k], 34816 B
  __shared__ u16 U[8192];           // union: QK: As[128][32] + Bs[128][32] | PV: Vt[128][32]
  __shared__ float Msh[2 * 128];
  __shared__ float Lsh[2 * 128];

  u16* As = U;
  u16* Bs = U + 4096;
  u16* Vt = U;

  int blk = blockIdx.x;
  int b = blk >> 4, ks = blk & 15;
  int t = threadIdx.x;
  int lane = t & 63, wv = t >> 6;
  int wm = wv & 1, wn = wv >> 1;        // 2x2 waves, each 64x64
  int m16 = lane & 15, quad = lane >> 4;

  const float* Qb  = Q  + (size_t)b * NH * DQK;
  const float* KVb = KV + (size_t)b * NKV * DQK;
  const int* idxp  = Idx + b * NTOP + ks * KC;

  // ---- QK phase: S[128h][128k] = Q[128][576] . K[128][576]^T ----
  int sr = t >> 1, sh = (t & 1) * 16;   // each thread stages 16 floats of one Q row and one K row
  int bidx = idxp[sr];
  const float* aq = Qb + (size_t)sr * DQK + sh;
  const float* bk = KVb + (size_t)bidx * DQK + sh;
  u16* aw = &As[sr * 32 + sh];
  u16* bw = &Bs[sr * 32 + sh];

  f32x4 acc[4][4] = {};

  float4 a0 = *(const float4*)(aq);
  float4 a1 = *(const float4*)(aq + 4);
  float4 a2 = *(const float4*)(aq + 8);
  float4 a3 = *(const float4*)(aq + 12);
  float4 b0 = *(const float4*)(bk);
  float4 b1 = *(const float4*)(bk + 4);
  float4 b2 = *(const float4*)(bk + 8);
  float4 b3 = *(const float4*)(bk + 12);

  for (int kk = 0; kk < 18; ++kk) {     // 576 / 32
    __syncthreads();
    {
      uint4 wa0 = { pk2(a0.x, a0.y), pk2(a0.z, a0.w), pk2(a1.x, a1.y), pk2(a1.z, a1.w) };
      uint4 wa1 = { pk2(a2.x, a2.y), pk2(a2.z, a2.w), pk2(a3.x, a3.y), pk2(a3.z, a3.w) };
      uint4 wb0 = { pk2(b0.x, b0.y), pk2(b0.z, b0.w), pk2(b1.x, b1.y), pk2(b1.z, b1.w) };
      uint4 wb1 = { pk2(b2.x, b2.y), pk2(b2.z, b2.w), pk2(b3.x, b3.y), pk2(b3.z, b3.w) };
      *(uint4*)aw = wa0; *(uint4*)(aw + 8) = wa1;
      *(uint4*)bw = wb0; *(uint4*)(bw + 8) = wb1;
    }
    __syncthreads();
    if (kk + 1 < 18) {
      const float* an = aq + (kk + 1) * 32;
      const float* bn = bk + (kk + 1) * 32;
      a0 = *(const float4*)(an);     a1 = *(const float4*)(an + 4);
      a2 = *(const float4*)(an + 8); a3 = *(const float4*)(an + 12);
      b0 = *(const float4*)(bn);     b1 = *(const float4*)(bn + 4);
      b2 = *(const float4*)(bn + 8); b3 = *(const float4*)(bn + 12);
    }
    bf16x8 af[4], bf[4];
#pragma unroll
    for (int i = 0; i < 4; ++i) af[i] = *(const bf16x8*)&As[(wm * 64 + i * 16 + m16) * 32 + quad * 8];
#pragma unroll
    for (int j = 0; j < 4; ++j) bf[j] = *(const bf16x8*)&Bs[(wn * 64 + j * 16 + m16) * 32 + quad * 8];
#pragma unroll
    for (int i = 0; i < 4; ++i)
#pragma unroll
      for (int j = 0; j < 4; ++j)
        acc[i][j] = __builtin_amdgcn_mfma_f32_16x16x32_bf16(af[i], bf[j], acc[i][j], 0, 0, 0);
  }

  // ---- chunk softmax (scores in acc, C layout: col=m16(key), row=quad*4+r(head)) ----
#pragma unroll
  for (int i = 0; i < 4; ++i)
#pragma unroll
    for (int j = 0; j < 4; ++j)
      acc[i][j] *= SCALE;

  float mx[4][4];
#pragma unroll
  for (int i = 0; i < 4; ++i)
#pragma unroll
    for (int r = 0; r < 4; ++r) {
      float v = fmaxf(fmaxf(acc[i][0][r], acc[i][1][r]), fmaxf(acc[i][2][r], acc[i][3][r]));
      v = fmaxf(v, __shfl_xor(v, 1)); v = fmaxf(v, __shfl_xor(v, 2));
      v = fmaxf(v, __shfl_xor(v, 4)); v = fmaxf(v, __shfl_xor(v, 8));
      mx[i][r] = v;
    }
  if (m16 == 0) {
#pragma unroll
    for (int i = 0; i < 4; ++i)
#pragma unroll
      for (int r = 0; r < 4; ++r)
        Msh[wn * 128 + wm * 64 + i * 16 + quad * 4 + r] = mx[i][r];
  }
  __syncthreads();
  float mrw[4][4];
#pragma unroll
  for (int i = 0; i < 4; ++i)
#pragma unroll
    for (int r = 0; r < 4; ++r) {
      int row = wm * 64 + i * 16 + quad * 4 + r;
      mrw[i][r] = fmaxf(Msh[row], Msh[128 + row]);
    }
  // exp in place, row sums
  float sm[4][4];
#pragma unroll
  for (int i = 0; i < 4; ++i)
#pragma unroll
    for (int r = 0; r < 4; ++r) {
      float s = 0.f;
#pragma unroll
      for (int j = 0; j < 4; ++j) {
        float e = expf(acc[i][j][r] - mrw[i][r]);
        acc[i][j][r] = e;
        s += e;
      }
      s += __shfl_xor(s, 1); s += __shfl_xor(s, 2);
      s += __shfl_xor(s, 4); s += __shfl_xor(s, 8);
      sm[i][r] = s;
    }
  if (m16 == 0) {
#pragma unroll
    for (int i = 0; i < 4; ++i)
#pragma unroll
      for (int r = 0; r < 4; ++r)
        Lsh[wn * 128 + wm * 64 + i * 16 + quad * 4 + r] = sm[i][r];
  }
  // scatter unnormalized P (bf16) into Psh
#pragma unroll
  for (int i = 0; i < 4; ++i)
#pragma unroll
    for (int j = 0; j < 4; ++j)
#pragma unroll
      for (int r = 0; r < 4; ++r) {
        int row = wm * 64 + i * 16 + quad * 4 + r;
        int col = wn * 64 + j * 16 + m16;
        Psh[row * PSTR + col] = (u16)bfbits(acc[i][j][r]);
      }
  __syncthreads();
  if (wn == 0 && m16 == 0) {
    float* mg = Mg + (b * NCH + ks) * NH;
    float* lg = Lg + (b * NCH + ks) * NH;
#pragma unroll
    for (int i = 0; i < 4; ++i)
#pragma unroll
      for (int r = 0; r < 4; ++r) {
        int row = wm * 64 + i * 16 + quad * 4 + r;
        mg[row] = mrw[i][r];
        lg[row] = Lsh[row] + Lsh[128 + row];
      }
  }

  // ---- PV phase: O_p[128h][512d] = P[128][128] . V[128][512] ----
  int p  = t & 15;        // key pair: keys 2p, 2p+1 of current 32-key step
  int dg = t >> 4;        // 16 d-groups of 8
  float* opb = Op + (((size_t)ks * NB + b) * NH) * DV;

  for (int dh = 0; dh < 4; ++dh) {      // 4 d-quarters of 128
    f32x4 a4[4][4] = {};
    for (int k2 = 0; k2 < 4; ++k2) {    // 128 keys / 32
      int key0 = k2 * 32 + p * 2;
      int i0 = idxp[key0], i1 = idxp[key0 + 1];
      const float* v0p = KVb + (size_t)i0 * DQK + dh * 128 + dg * 8;
      const float* v1p = KVb + (size_t)i1 * DQK + dh * 128 + dg * 8;
      float4 x0 = *(const float4*)(v0p);
      float4 x1 = *(const float4*)(v0p + 4);
      float4 y0 = *(const float4*)(v1p);
      float4 y1 = *(const float4*)(v1p + 4);
      unsigned lo[8] = { bfbits(x0.x), bfbits(x0.y), bfbits(x0.z), bfbits(x0.w),
                         bfbits(x1.x), bfbits(x1.y), bfbits(x1.z), bfbits(x1.w) };
      unsigned hi[8] = { bfbits(y0.x), bfbits(y0.y), bfbits(y0.z), bfbits(y0.w),
                         bfbits(y1.x), bfbits(y1.y), bfbits(y1.z), bfbits(y1.w) };
      __syncthreads();
      // transposed store: Vt[d][k], b32 = packed key pair; chunk-XOR swizzle kills d-stride conflicts
      int chunk = (p >> 2) ^ (dg & 3);
#pragma unroll
      for (int jj = 0; jj < 8; ++jj) {
        int row = dg * 8 + jj;
        int elem = row * 32 + chunk * 8 + (p & 3) * 2;
        *(unsigned*)&Vt[elem] = lo[jj] | (hi[jj] << 16);
      }
      __syncthreads();
      bf16x8 af2[4], bf2[4];
#pragma unroll
      for (int i = 0; i < 4; ++i)
        af2[i] = *(const bf16x8*)&Psh[(wm * 64 + i * 16 + m16) * PSTR + k2 * 32 + quad * 8];
#pragma unroll
      for (int j = 0; j < 4; ++j) {
        int row = wn * 64 + j * 16 + m16;
        int rchunk = quad ^ ((row >> 3) & 3);
        bf2[j] = *(const bf16x8*)&Vt[row * 32 + rchunk * 8];
      }
#pragma unroll
      for (int i = 0; i < 4; ++i)
#pragma unroll
        for (int j = 0; j < 4; ++j)
          a4[i][j] = __builtin_amdgcn_mfma_f32_16x16x32_bf16(af2[i], bf2[j], a4[i][j], 0, 0, 0);
    }
    // store partials (fp32)
#pragma unroll
    for (int i = 0; i < 4; ++i)
#pragma unroll
      for (int j = 0; j < 4; ++j)
#pragma unroll
        for (int r = 0; r < 4; ++r) {
          int h = wm * 64 + i * 16 + quad * 4 + r;
          int d = dh * 128 + wn * 64 + j * 16 + m16;
          opb[(size_t)h * DV + d] = a4[i][j][r];
        }
  }
}

// ---------------- combine: exact log-sum-exp merge of 16 chunk partials ----------------
__global__ __launch_bounds__(256) void combine(const float* __restrict__ Op, const float* __restrict__ Mg,
                                               const float* __restrict__ Lg, float* __restrict__ Out) {
  int row = blockIdx.x;            // b*128 + h
  int b = row >> 7, h = row & 127;
  int t = threadIdx.x;

  float m[NCH], l[NCH];
#pragma unroll
  for (int c = 0; c < NCH; ++c) {
    m[c] = Mg[(b * NCH + c) * NH + h];
    l[c] = Lg[(b * NCH + c) * NH + h];
  }
  float M = m[0];
#pragma unroll
  for (int c = 1; c < NCH; ++c) M = fmaxf(M, m[c]);
  float L = 0.f, w[NCH];
#pragma unroll
  for (int c = 0; c < NCH; ++c) { w[c] = expf(m[c] - M); L += l[c] * w[c]; }
  float inv = 1.0f / L;

  float ox = 0.f, oy = 0.f;
#pragma unroll
  for (int c = 0; c < NCH; ++c) {
    const float* src = Op + (((size_t)c * NB + b) * NH + h) * DV + t * 2;
    float2 v = *(const float2*)src;
    ox += w[c] * v.x; oy += w[c] * v.y;
  }
  float2 o = { ox * inv, oy * inv };
  *(float2*)(Out + ((size_t)b * NH + h) * DV + t * 2) = o;
}

extern "C" void kernel_launch(void* const* d_in, const int* in_sizes, int n_in,
                              void* d_out, int out_size, void* d_ws, size_t ws_size,
                              hipStream_t stream) {
  const float* Q  = (const float*)d_in[0];
  const float* KV = (const float*)d_in[1];
  const int*  Idx = (const int*)d_in[2];

  char* ws = (char*)d_ws;
  float* Op = (float*)(ws + OFF_OP);
  float* Mg = (float*)(ws + OFF_M);
  float* Lg = (float*)(ws + OFF_L);
  float* Out = (float*)d_out;

  flash_chunk<<<dim3(NB * NCH), dim3(256), 0, stream>>>(Q, KV, Idx, Op, Mg, Lg);
  combine<<<dim3(NB * NH), dim3(256), 0, stream>>>(Op, Mg, Lg, Out);
}